// Round 9
// baseline (412.460 us; speedup 1.0000x reference)
//
#include <hip/hip_runtime.h>
#include <hip/hip_bf16.h>
#include <stdint.h>

typedef __attribute__((ext_vector_type(4))) float f32x4;
typedef __attribute__((ext_vector_type(8))) short s16x8;
typedef __attribute__((ext_vector_type(4))) unsigned short u16x4;
typedef __attribute__((ext_vector_type(4))) int i32x4;

#define B2T 16384
#define BH 8192
#define DIN 1024
#define DD1 512
#define DIMS 256
#define NC 40
#define CAPS 2048

__device__ __forceinline__ unsigned short f2b(float f) {
  unsigned int u = __builtin_bit_cast(unsigned int, f);
  u += 0x7FFFu + ((u >> 16) & 1u);
  return (unsigned short)(u >> 16);
}

__device__ __forceinline__ float b2f(unsigned short u) {
  return __builtin_bit_cast(float, ((unsigned int)u) << 16);
}

// async global->LDS DMA, 16B per lane; LDS dst is wave-uniform base + lane*16
__device__ __forceinline__ void gload16(const void* g, void* l) {
  __builtin_amdgcn_global_load_lds(
      (const __attribute__((address_space(1))) void*)g,
      (__attribute__((address_space(3))) void*)l, 16, 0, 0);
}

// forward-only phase chaining: producer blocks signal once; consumer blocks have ONE
// thread poll a device-scope counter (relaxed, s_sleep between polls), then one acquire
// fence. No repeated barriers, no per-poll invalidates (round-4 lesson). Blocks launch
// in phase order, so most waits are satisfied on entry.
__device__ __forceinline__ void sig(unsigned* f) {
  __builtin_amdgcn_fence(__ATOMIC_RELEASE, "agent");
  __syncthreads();
  if (threadIdx.x == 0)
    __hip_atomic_fetch_add(f, 1u, __ATOMIC_RELAXED, __HIP_MEMORY_SCOPE_AGENT);
}
__device__ __forceinline__ void waitf(unsigned* f, unsigned n) {
  if (threadIdx.x == 0) {
    while (__hip_atomic_load(f, __ATOMIC_RELAXED, __HIP_MEMORY_SCOPE_AGENT) < n)
      __builtin_amdgcn_s_sleep(32);
  }
  __syncthreads();
  __builtin_amdgcn_fence(__ATOMIC_ACQUIRE, "agent");
}

// ---------------- prep_all: Weff FIRST, then transposes, then hcvt (stream hides) ----------
// Weff blocks (long, VALU/LDS-bound) dispatch first; hcvt blocks (1024, HBM-bound) last so
// the 96MB stream overlaps the Weff tail instead of serializing before it (round-6 lesson).
__global__ __launch_bounds__(256) void prep_all(const float* __restrict__ lufeat,
                                                unsigned short* __restrict__ lufeatH,
                                                const float* __restrict__ W1,
                                                const float* __restrict__ W2,
                                                const float* __restrict__ b1,
                                                const float* __restrict__ b2,
                                                const float* __restrict__ W3,
                                                const float* __restrict__ W4,
                                                unsigned short* __restrict__ WeffT,
                                                float* __restrict__ beff,
                                                unsigned short* __restrict__ W3T,
                                                unsigned short* __restrict__ W4T,
                                                float* __restrict__ statz) {
  __shared__ float W1s[32][36];
  __shared__ float W2sT[32][36];
  int b = blockIdx.x, t = threadIdx.x;
  if (b < 256) {
    int k0 = (b & 31) * 32, n0 = (b >> 5) * 32;
    int nn = t & 31, kq = t >> 5;  // kq in 0..7
    f32x4 acc = (f32x4){0.f, 0.f, 0.f, 0.f};
    for (int j0 = 0; j0 < DD1; j0 += 32) {
#pragma unroll
      for (int i = 0; i < 4; ++i) {
        int idx = t + 256 * i;
        int kk = idx >> 5, jj = idx & 31;
        W1s[kk][jj] = W1[(size_t)(k0 + kk) * DD1 + j0 + jj];
        W2sT[jj][kk] = W2[(size_t)(j0 + kk) * DIMS + n0 + jj];
      }
      __syncthreads();
#pragma unroll
      for (int jj4 = 0; jj4 < 8; ++jj4) {
        f32x4 w2 = *(const f32x4*)&W2sT[nn][jj4 * 4];
        f32x4 w1_0 = *(const f32x4*)&W1s[kq * 4 + 0][jj4 * 4];
        f32x4 w1_1 = *(const f32x4*)&W1s[kq * 4 + 1][jj4 * 4];
        f32x4 w1_2 = *(const f32x4*)&W1s[kq * 4 + 2][jj4 * 4];
        f32x4 w1_3 = *(const f32x4*)&W1s[kq * 4 + 3][jj4 * 4];
        acc[0] += w1_0[0] * w2[0] + w1_0[1] * w2[1] + w1_0[2] * w2[2] + w1_0[3] * w2[3];
        acc[1] += w1_1[0] * w2[0] + w1_1[1] * w2[1] + w1_1[2] * w2[2] + w1_1[3] * w2[3];
        acc[2] += w1_2[0] * w2[0] + w1_2[1] * w2[1] + w1_2[2] * w2[2] + w1_2[3] * w2[3];
        acc[3] += w1_3[0] * w2[0] + w1_3[1] * w2[1] + w1_3[2] * w2[2] + w1_3[3] * w2[3];
      }
      __syncthreads();
    }
    u16x4 pk = {f2b(acc[0]), f2b(acc[1]), f2b(acc[2]), f2b(acc[3])};
    *(u16x4*)(WeffT + (size_t)(n0 + nn) * DIN + k0 + kq * 4) = pk;
  } else if (b == 256) {
    float a0 = 0.f, a1 = 0.f, a2 = 0.f, a3 = 0.f, a4 = 0.f, a5 = 0.f, a6 = 0.f, a7 = 0.f;
    for (int j = 0; j < DD1; j += 8) {
      a0 += b1[j + 0] * W2[(size_t)(j + 0) * DIMS + t];
      a1 += b1[j + 1] * W2[(size_t)(j + 1) * DIMS + t];
      a2 += b1[j + 2] * W2[(size_t)(j + 2) * DIMS + t];
      a3 += b1[j + 3] * W2[(size_t)(j + 3) * DIMS + t];
      a4 += b1[j + 4] * W2[(size_t)(j + 4) * DIMS + t];
      a5 += b1[j + 5] * W2[(size_t)(j + 5) * DIMS + t];
      a6 += b1[j + 6] * W2[(size_t)(j + 6) * DIMS + t];
      a7 += b1[j + 7] * W2[(size_t)(j + 7) * DIMS + t];
    }
    beff[t] = b2[t] + (((a0 + a1) + (a2 + a3)) + ((a4 + a5) + (a6 + a7)));
  } else if (b < 577) {
    int idx = (b - 257) * 256 + t;
    int n = idx / 320, k = idx - n * 320;
    float v = (k < 296) ? W3[(size_t)k * 256 + n] : 0.0f;
    W3T[(size_t)n * 320 + k] = f2b(v);
  } else if (b < 641) {
    int idx = (b - 577) * 256 + t;
    int n = idx >> 8, k = idx & 255;
    W4T[(size_t)n * 256 + k] = f2b(W4[(size_t)k * 64 + n]);
  } else if (b == 641) {
    for (int i = t; i < 684; i += 256) statz[i] = 0.0f;  // 640 stats + 40 msq + 4 flags
  } else {
    // hcvt: same f2b RNE as all staging paths -> downstream bit-identical
    size_t base = (size_t)(b - 642) * 16384 + (size_t)t * 8;
#pragma unroll
    for (int i = 0; i < 8; ++i) {
      size_t idx = base + (size_t)i * 2048;
      f32x4 v0 = *(const f32x4*)(lufeat + idx);
      f32x4 v1 = *(const f32x4*)(lufeat + idx + 4);
      s16x8 p;
      p[0] = (short)f2b(v0[0]); p[1] = (short)f2b(v0[1]);
      p[2] = (short)f2b(v0[2]); p[3] = (short)f2b(v0[3]);
      p[4] = (short)f2b(v1[0]); p[5] = (short)f2b(v1[1]);
      p[6] = (short)f2b(v1[2]); p[7] = (short)f2b(v1[3]);
      *(s16x8*)(lufeatH + idx) = p;
    }
  }
}

// ---------------- gemm1: pure-DMA bf16 MFMA, 512 blocks x 256 thr, 32x256 tile --------------
// (verified rounds 6-7, ~10us) A and B staged via global_load_lds, XOR-swizzled both sides.
__global__ __launch_bounds__(256) void gemm1_dma(
    const unsigned short* __restrict__ AH, const unsigned short* __restrict__ BT,
    const float* __restrict__ bias, float* __restrict__ C,
    unsigned short* __restrict__ uf) {
  __shared__ __align__(16) char A_s[2][4096];   // 32 rows x 64 k bf16
  __shared__ __align__(16) char B_s[2][32768];  // 256 rows x 64 k bf16
  __shared__ float rs[4][32];
  int t = threadIdx.x, m0 = blockIdx.x * 32;
  int w = t >> 6, lane = t & 63, q = lane >> 4, ln = lane & 15;
  f32x4 acc[2][4];
#pragma unroll
  for (int mi = 0; mi < 2; ++mi)
#pragma unroll
    for (int ni = 0; ni < 4; ++ni) acc[mi][ni] = (f32x4){0.f, 0.f, 0.f, 0.f};

  auto dma = [&](int s, int bufi) {
    int kb = s * 64;
    {
      int row = t >> 3, j = t & 7;
      gload16(AH + (size_t)(m0 + row) * 1024 + kb + ((j ^ (row & 7)) * 8),
              A_s[bufi] + t * 16);
    }
#pragma unroll
    for (int i = 0; i < 8; ++i) {
      int ch = t + 256 * i, n = ch >> 3, j = ch & 7;
      gload16(BT + (size_t)n * 1024 + kb + ((j ^ (n & 7)) * 8),
              B_s[bufi] + (w * 64 + 256 * i) * 16);
    }
  };

  auto compute = [&](int bufi) {
#pragma unroll
    for (int k32 = 0; k32 < 64; k32 += 32) {
      int koff = (k32 + q * 8) * 2;
      s16x8 af[2];
#pragma unroll
      for (int mi = 0; mi < 2; ++mi) {
        int row = mi * 16 + ln;
        af[mi] = *(const s16x8*)(A_s[bufi] + ((row * 128 + koff) ^ ((row & 7) << 4)));
      }
      int nb0 = w * 64;
#pragma unroll
      for (int ni = 0; ni < 4; ++ni) {
        int brow = nb0 + ni * 16 + ln;
        s16x8 bfr = *(const s16x8*)(B_s[bufi] + ((brow * 128 + koff) ^ ((brow & 7) << 4)));
#pragma unroll
        for (int mi = 0; mi < 2; ++mi)
          acc[mi][ni] = __builtin_amdgcn_mfma_f32_16x16x32_bf16(af[mi], bfr, acc[mi][ni], 0, 0, 0);
      }
    }
  };

  dma(0, 0);
  __syncthreads();
  for (int s = 0; s < 16; ++s) {
    if (s + 1 < 16) dma(s + 1, (s + 1) & 1);
    compute(s & 1);
    __syncthreads();
  }

  float v[2][4][4];
#pragma unroll
  for (int mi = 0; mi < 2; ++mi)
#pragma unroll
    for (int ni = 0; ni < 4; ++ni) {
      float bv = bias[w * 64 + ni * 16 + ln];
#pragma unroll
      for (int r = 0; r < 4; ++r) v[mi][ni][r] = acc[mi][ni][r] + bv;
    }
  float p[2][4];
#pragma unroll
  for (int mi = 0; mi < 2; ++mi)
#pragma unroll
    for (int r = 0; r < 4; ++r) {
      float s = v[mi][0][r] * v[mi][0][r] + v[mi][1][r] * v[mi][1][r] +
                v[mi][2][r] * v[mi][2][r] + v[mi][3][r] * v[mi][3][r];
      s += __shfl_xor(s, 1); s += __shfl_xor(s, 2);
      s += __shfl_xor(s, 4); s += __shfl_xor(s, 8);
      p[mi][r] = s;
    }
  if (ln == 0) {
#pragma unroll
    for (int mi = 0; mi < 2; ++mi)
#pragma unroll
      for (int r = 0; r < 4; ++r) rs[w][mi * 16 + q * 4 + r] = p[mi][r];
  }
  __syncthreads();
  if (t < 32) {
    float s = rs[0][t] + rs[1][t] + rs[2][t] + rs[3][t];
    rs[0][t] = rsqrtf(s);
  }
  __syncthreads();
#pragma unroll
  for (int mi = 0; mi < 2; ++mi)
#pragma unroll
    for (int r = 0; r < 4; ++r) {
      int ribf = mi * 16 + q * 4 + r;
      float inv = rs[0][ribf];
      int grow = m0 + ribf;
#pragma unroll
      for (int ni = 0; ni < 4; ++ni) {
        int col = w * 64 + ni * 16 + ln;
        float nv = v[mi][ni][r] * inv;
        if (grow < BH)
          C[(size_t)grow * DIMS + col] = nv;
        else
          uf[(size_t)(grow - BH) * 320 + col] = f2b(nv);
      }
    }
}

// ---------------- back_all: bank(160) > dist(512) > gemm2(512) > gemm3(128) > uscore(512) ---
// One kernel, flag-chained phases (phase bodies = round-7 verified kernels verbatim).
// LDS 75264 -> 2 blocks/CU (residency verified round 4). flags zeroed by prep_all.
__global__ __launch_bounds__(256) void back_all(
    const int* llabel, const float* Hn, const float* mbank0, const float* start0,
    float* mbank, float* msq, float* lscores, unsigned short* uf,
    const unsigned short* W3T, const float* b3, float* ybuf,
    float* sums1, float* ssq1, const float* g1, const float* be1,
    const unsigned short* W4T, const float* b4, float* y2,
    float* sums2, float* ssq2, const float* g2, const float* be2,
    const float* W5, const float* b5, float* uscores, unsigned* flags) {
  __shared__ __align__(16) char smem[75264];
  const int bx = blockIdx.x, t = threadIdx.x;
  const int w = t >> 6, lane = t & 63, q = lane >> 4, ln = lane & 15;
  const float l09 = -0.15200309344504997f;  // log2(0.9)

  if (bx < 160) {
    // ---------- bank: memory-bank EMA, 4-way D-split ----------
    int c = bx >> 2, dq = bx & 3;
    int* lab_s = (int*)smem;
    int* idx_s = (int*)(smem + 32768);
    float* redp = (float*)(smem + 40960);
    int* wcnt = (int*)(smem + 41984);
    for (int i = t; i < BH / 4; i += 256) ((i32x4*)lab_s)[i] = ((const i32x4*)llabel)[i];
    __syncthreads();
    int base0 = w * (BH / 4);
    int cnt = 0;
    for (int b = 0; b < BH / 4; b += 64)
      cnt += (int)__popcll(__ballot(lab_s[base0 + b + lane] == c));
    if (lane == 0) wcnt[w] = cnt;
    __syncthreads();
    int off = 0;
#pragma unroll
    for (int i = 0; i < 4; ++i)
      if (i < w) off += wcnt[i];
    int Ktot = wcnt[0] + wcnt[1] + wcnt[2] + wcnt[3];
    int running = off;
    for (int b = 0; b < BH / 4; b += 64) {
      bool hit = lab_s[base0 + b + lane] == c;
      unsigned long long mk = __ballot(hit);
      if (hit) {
        int pos = running + (int)__popcll(mk & ((1ull << lane) - 1ull));
        if (pos < CAPS) idx_s[pos] = base0 + b + lane;
      }
      running += (int)__popcll(mk);
    }
    __syncthreads();
    int K = Ktot < CAPS ? Ktot : CAPS;
    bool fresh = (start0[c] == 0.0f);
    int dcol = t & 63, rr = t >> 6;
    int d = dq * 64 + dcol;
    float p0 = 0.f, p1 = 0.f, p2 = 0.f, p3 = 0.f;
    if (K > 0) {
      float w0fold = fresh ? exp2f((float)K * l09) : 0.f;
      int m = rr;
      for (; m + 12 < K; m += 16) {
        float e = (float)(K - 1 - m);
        float wa = 0.1f * exp2f(e * l09) + (m == 0 ? w0fold : 0.f);
        p0 += wa * Hn[(size_t)idx_s[m] * DIMS + d];
        p1 += 0.1f * exp2f((e - 4.f) * l09) * Hn[(size_t)idx_s[m + 4] * DIMS + d];
        p2 += 0.1f * exp2f((e - 8.f) * l09) * Hn[(size_t)idx_s[m + 8] * DIMS + d];
        p3 += 0.1f * exp2f((e - 12.f) * l09) * Hn[(size_t)idx_s[m + 12] * DIMS + d];
      }
      for (; m < K; m += 4) {
        float wa = 0.1f * exp2f((float)(K - 1 - m) * l09) + (m == 0 ? w0fold : 0.f);
        p0 += wa * Hn[(size_t)idx_s[m] * DIMS + d];
      }
    }
    redp[rr * 64 + dcol] = (p0 + p1) + (p2 + p3);
    __syncthreads();
    if (t < 64) {
      int dd = dq * 64 + t;
      float out;
      if (K == 0) {
        out = mbank0[(size_t)c * DIMS + dd];
      } else {
        float base_v = fresh ? 0.f : exp2f((float)K * l09) * mbank0[(size_t)c * DIMS + dd];
        out = ((redp[t] + redp[64 + t]) + (redp[128 + t] + redp[192 + t])) + base_v;
      }
      mbank[(size_t)c * DIMS + dd] = out;
      float vv = out * out;
#pragma unroll
      for (int o = 32; o; o >>= 1) vv += __shfl_xor(vv, o);
      if (t == 0) atomicAdd(&msq[c], vv);
    }
    sig(flags + 0);
  } else if (bx < 672) {
    // ---------- dist: 32 rows/block ----------
    waitf(flags + 0, 160u);
    int db = bx - 160;
    float* Ms = (float*)smem;
    float* Hs = (float*)(smem + 41600);
    float* msq_s = (float*)(smem + 74880);
    int r0 = db * 32;
    for (int e = t; e < NC * 64; e += 256) {
      int i = e >> 6, d0 = (e & 63) * 4;
      *(f32x4*)&Ms[i * 260 + d0] = *(const f32x4*)(mbank + (size_t)i * DIMS + d0);
    }
    if (r0 < BH) {
      for (int e = t; e < 32 * 64; e += 256) {
        int i = e >> 6, d0 = (e & 63) * 4;
        *(f32x4*)&Hs[i * 260 + d0] = *(const f32x4*)(Hn + (size_t)(r0 + i) * DIMS + d0);
      }
    } else {
      for (int e = t; e < 32 * 32; e += 256) {
        int i = e >> 5, d0 = (e & 31) * 8;
        s16x8 vb = *(const s16x8*)(uf + (size_t)(r0 - BH + i) * 320 + d0);
#pragma unroll
        for (int j = 0; j < 8; ++j) Hs[i * 260 + d0 + j] = b2f((unsigned short)vb[j]);
      }
    }
    if (t < NC) msq_s[t] = msq[t];
    __syncthreads();
    int r = t >> 3, c0 = (t & 7) * 5;
    float g0 = 0, g1v = 0, g2v = 0, g3 = 0, g4 = 0;
    for (int d = 0; d < DIMS; d += 4) {
      f32x4 f = *(const f32x4*)&Hs[r * 260 + d];
      f32x4 m0v = *(const f32x4*)&Ms[(c0 + 0) * 260 + d];
      f32x4 m1v = *(const f32x4*)&Ms[(c0 + 1) * 260 + d];
      f32x4 m2v = *(const f32x4*)&Ms[(c0 + 2) * 260 + d];
      f32x4 m3v = *(const f32x4*)&Ms[(c0 + 3) * 260 + d];
      f32x4 m4v = *(const f32x4*)&Ms[(c0 + 4) * 260 + d];
      g0 += f[0] * m0v[0] + f[1] * m0v[1] + f[2] * m0v[2] + f[3] * m0v[3];
      g1v += f[0] * m1v[0] + f[1] * m1v[1] + f[2] * m1v[2] + f[3] * m1v[3];
      g2v += f[0] * m2v[0] + f[1] * m2v[1] + f[2] * m2v[2] + f[3] * m2v[3];
      g3 += f[0] * m3v[0] + f[1] * m3v[1] + f[2] * m3v[2] + f[3] * m3v[3];
      g4 += f[0] * m4v[0] + f[1] * m4v[1] + f[2] * m4v[2] + f[3] * m4v[3];
    }
    int row = r0 + r;
    float d2[5];
    d2[0] = 1.0f + msq_s[c0 + 0] - 2.0f * g0;
    d2[1] = 1.0f + msq_s[c0 + 1] - 2.0f * g1v;
    d2[2] = 1.0f + msq_s[c0 + 2] - 2.0f * g2v;
    d2[3] = 1.0f + msq_s[c0 + 3] - 2.0f * g3;
    d2[4] = 1.0f + msq_s[c0 + 4] - 2.0f * g4;
    if (row < BH) {
      float mn = fminf(fminf(fminf(d2[0], d2[1]), fminf(d2[2], d2[3])), d2[4]);
      mn = fminf(mn, __shfl_xor(mn, 1, 8));
      mn = fminf(mn, __shfl_xor(mn, 2, 8));
      mn = fminf(mn, __shfl_xor(mn, 4, 8));
      if ((t & 7) == 0) lscores[row] = sqrtf(fmaxf(mn, 0.0f));
    } else {
      unsigned short* dst = uf + (size_t)(row - BH) * 320 + 256 + c0;
#pragma unroll
      for (int qq = 0; qq < 5; ++qq) dst[qq] = f2b(sqrtf(fmaxf(d2[qq], 0.0f)));
    }
    sig(flags + 1);
  } else if (bx < 1184) {
    // ---------- gemm2: uf @ W3T + b3 -> ybuf, bnstat1 (pure-DMA, 16x256 tile) ----------
    waitf(flags + 1, 512u);
    int gb = bx - 672;
    char* A_s = smem;            // [2][2048]
    char* B_s = smem + 4096;     // [2][32768]
    int m0 = gb * 16;
    f32x4 acc[4];
#pragma unroll
    for (int ni = 0; ni < 4; ++ni) acc[ni] = (f32x4){0.f, 0.f, 0.f, 0.f};

    auto dma = [&](int s, int bufi) {
      int kb = s * 64;
      if (t < 128) {
        int row = t >> 3, j = t & 7;
        gload16(uf + (size_t)(m0 + row) * 320 + kb + ((j ^ (row & 7)) * 8),
                A_s + bufi * 2048 + t * 16);
      }
#pragma unroll
      for (int i = 0; i < 8; ++i) {
        int ch = t + 256 * i, n = ch >> 3, j = ch & 7;
        gload16(W3T + (size_t)n * 320 + kb + ((j ^ (n & 7)) * 8),
                B_s + bufi * 32768 + (w * 64 + 256 * i) * 16);
      }
    };
    auto compute = [&](int bufi) {
#pragma unroll
      for (int k32 = 0; k32 < 64; k32 += 32) {
        int koff = (k32 + q * 8) * 2;
        int arow = ln;
        s16x8 af = *(const s16x8*)(A_s + bufi * 2048 + ((arow * 128 + koff) ^ ((arow & 7) << 4)));
        int nb0 = w * 64;
#pragma unroll
        for (int ni = 0; ni < 4; ++ni) {
          int brow = nb0 + ni * 16 + ln;
          s16x8 bfr = *(const s16x8*)(B_s + bufi * 32768 + ((brow * 128 + koff) ^ ((brow & 7) << 4)));
          acc[ni] = __builtin_amdgcn_mfma_f32_16x16x32_bf16(af, bfr, acc[ni], 0, 0, 0);
        }
      }
    };
    dma(0, 0);
    __syncthreads();
    for (int s = 0; s < 5; ++s) {
      if (s + 1 < 5) dma(s + 1, (s + 1) & 1);
      compute(s & 1);
      __syncthreads();
    }
#pragma unroll
    for (int ni = 0; ni < 4; ++ni) {
      int col = w * 64 + ni * 16 + ln;
      float bv = b3[col];
      float s = 0.f, s2 = 0.f;
#pragma unroll
      for (int r = 0; r < 4; ++r) {
        float x = acc[ni][r] + bv;
        ybuf[(size_t)(m0 + q * 4 + r) * 256 + col] = x;
        s += x; s2 += x * x;
      }
      s += __shfl_xor(s, 16); s += __shfl_xor(s, 32);
      s2 += __shfl_xor(s2, 16); s2 += __shfl_xor(s2, 32);
      if (q == 0) {
        atomicAdd(&sums1[col], s);
        atomicAdd(&ssq1[col], s2);
      }
    }
    sig(flags + 2);
  } else if (bx < 1312) {
    // ---------- gemm3: relu(bn1(ybuf)) @ W4T + b4 -> y2, bnstat2 ----------
    waitf(flags + 2, 512u);
    int hb = bx - 1184;
    short* A3 = (short*)smem;              // [2][64][72]
    char* B3 = smem + 18432;               // [2][8192]
    float* bsc = (float*)(smem + 34816);   // 256
    float* bsh = (float*)(smem + 35840);   // 256
    {
      float mu = sums1[t] * (1.0f / 8192.0f);
      float var = ssq1[t] * (1.0f / 8192.0f) - mu * mu;
      float sc = g1[t] * rsqrtf(var + 1e-5f);
      bsc[t] = sc;
      bsh[t] = be1[t] - mu * sc;
    }
    __syncthreads();
    int m0 = hb * 64;
    f32x4 acc[4];
#pragma unroll
    for (int ni = 0; ni < 4; ++ni) acc[ni] = (f32x4){0.f, 0.f, 0.f, 0.f};
    f32x4 pa0[2][2], pa1[2][2];
    auto issueA3 = [&](int kbase, f32x4 (&pa)[2][2]) {
#pragma unroll
      for (int i = 0; i < 2; ++i) {
        int ch = t + 256 * i, row = ch >> 3, kp = (ch & 7) * 8;
        const f32x4* src = (const f32x4*)(ybuf + (size_t)(m0 + row) * 256 + kbase + kp);
        pa[i][0] = src[0];
        pa[i][1] = src[1];
      }
    };
    auto stageA3 = [&](int kbase, int bufi, f32x4 (&pa)[2][2]) {
#pragma unroll
      for (int i = 0; i < 2; ++i) {
        int ch = t + 256 * i, row = ch >> 3, kp = (ch & 7) * 8;
        float vv[8] = {pa[i][0][0], pa[i][0][1], pa[i][0][2], pa[i][0][3],
                       pa[i][1][0], pa[i][1][1], pa[i][1][2], pa[i][1][3]};
#pragma unroll
        for (int j = 0; j < 8; ++j) {
          int f = kbase + kp + j;
          vv[j] = fmaxf(vv[j] * bsc[f] + bsh[f], 0.0f);
        }
        s16x8 p;
        p[0] = (short)f2b(vv[0]); p[1] = (short)f2b(vv[1]);
        p[2] = (short)f2b(vv[2]); p[3] = (short)f2b(vv[3]);
        p[4] = (short)f2b(vv[4]); p[5] = (short)f2b(vv[5]);
        p[6] = (short)f2b(vv[6]); p[7] = (short)f2b(vv[7]);
        *(s16x8*)&A3[(bufi * 64 + row) * 72 + kp] = p;
      }
    };
    auto gloadB3 = [&](int kbase, int bufi) {
#pragma unroll
      for (int i = 0; i < 2; ++i) {
        int ch = t + 256 * i, n = ch >> 3, j = ch & 7;
        gload16(W4T + (size_t)n * 256 + kbase + ((j ^ (n & 7)) * 8),
                B3 + bufi * 8192 + ch * 16);
      }
    };
    auto compute3 = [&](int cur) {
#pragma unroll
      for (int k32 = 0; k32 < 64; k32 += 32) {
        s16x8 af = *(const s16x8*)&A3[(cur * 64 + w * 16 + ln) * 72 + k32 + q * 8];
#pragma unroll
        for (int ni = 0; ni < 4; ++ni) {
          int brow = ni * 16 + ln;
          int bb = (brow * 128 + (k32 + q * 8) * 2) ^ ((brow & 7) << 4);
          s16x8 bfr = *(const s16x8*)(B3 + cur * 8192 + bb);
          acc[ni] = __builtin_amdgcn_mfma_f32_16x16x32_bf16(af, bfr, acc[ni], 0, 0, 0);
        }
      }
    };
    issueA3(0, pa0);
    gloadB3(0, 0);
    stageA3(0, 0, pa0);
    issueA3(64, pa1);
    __syncthreads();
    for (int s = 0; s < 4; ++s) {
      int cur = s & 1;
      if (s + 1 < 4) gloadB3((s + 1) << 6, cur ^ 1);
      if (s + 2 < 4) issueA3((s + 2) << 6, (s & 1) ? pa1 : pa0);
      compute3(cur);
      if (s + 1 < 4) stageA3((s + 1) << 6, cur ^ 1, (s & 1) ? pa0 : pa1);
      __syncthreads();
    }
#pragma unroll
    for (int ni = 0; ni < 4; ++ni) {
      int col = ni * 16 + ln;
      float bv = b4[col];
      float s = 0.f, s2 = 0.f;
#pragma unroll
      for (int r = 0; r < 4; ++r) {
        float x = acc[ni][r] + bv;
        y2[(size_t)(m0 + w * 16 + q * 4 + r) * 64 + col] = x;
        s += x; s2 += x * x;
      }
      s += __shfl_xor(s, 16); s += __shfl_xor(s, 32);
      s2 += __shfl_xor(s2, 16); s2 += __shfl_xor(s2, 32);
      if (q == 0) {
        atomicAdd(&sums2[col], s);
        atomicAdd(&ssq2[col], s2);
      }
    }
    sig(flags + 3);
  } else {
    // ---------- uscore: 512 blocks x 16 rows ----------
    waitf(flags + 3, 128u);
    int ub = bx - 1312;
    float mu = sums2[lane] * (1.0f / 8192.0f);
    float var = ssq2[lane] * (1.0f / 8192.0f) - mu * mu;
    float sc = g2[lane] * rsqrtf(var + 1e-5f);
    float sh = be2[lane] - mu * sc;
    float w5 = W5[lane];
    float bb5 = b5[0];
#pragma unroll
    for (int i = 0; i < 4; ++i) {
      int row = ub * 16 + i * 4 + w;
      float v = fmaxf(y2[(size_t)row * 64 + lane] * sc + sh, 0.0f) * w5;
#pragma unroll
      for (int o = 32; o; o >>= 1) v += __shfl_xor(v, o);
      if (lane == 0) uscores[row] = v + bb5;
    }
  }
}

extern "C" void kernel_launch(void* const* d_in, const int* in_sizes, int n_in,
                              void* d_out, int out_size, void* d_ws, size_t ws_size,
                              hipStream_t stream) {
  const float* lufeat = (const float*)d_in[0];
  const int* llabel = (const int*)d_in[1];
  const float* W1 = (const float*)d_in[2];
  const float* b1 = (const float*)d_in[3];
  const float* W2 = (const float*)d_in[4];
  const float* b2 = (const float*)d_in[5];
  const float* W3 = (const float*)d_in[6];
  const float* b3 = (const float*)d_in[7];
  const float* W4 = (const float*)d_in[8];
  const float* b4 = (const float*)d_in[9];
  const float* W5 = (const float*)d_in[10];
  const float* b5 = (const float*)d_in[11];
  const float* g1 = (const float*)d_in[12];
  const float* be1 = (const float*)d_in[13];
  const float* g2 = (const float*)d_in[14];
  const float* be2 = (const float*)d_in[15];
  const float* mbank0 = (const float*)d_in[16];
  const float* start0 = (const float*)d_in[17];

  // workspace layout (lifetimes checked — no cross-lifetime aliasing):
  char* ws = (char*)d_ws;
  unsigned short* WeffT = (unsigned short*)(ws + 0);       // [0, 524288)
  float* Hraw = (float*)(ws + 524288);                     // lower 8192x256 f32 only
  float* ybuf = (float*)(ws + 524288);                     // lower half of Hraw (dead after dist)
  float* y2 = (float*)(ws + 8912896);                      // upper region
  unsigned short* uf = (unsigned short*)(ws + 17301504);   // 8192x320 bf16
  unsigned short* W3T = (unsigned short*)(ws + 22544384);  // 256x320 bf16
  unsigned short* W4T = (unsigned short*)(ws + 22708224);  // 64x256 bf16
  float* beff = (float*)(ws + 22740992);                   // 256 f32
  float* sums1 = (float*)(ws + 22742016);                  // 256 (zeroed by prep_all)
  float* ssq1 = sums1 + 256;                               // 256
  float* sums2 = ssq1 + 256;                               // 64
  float* ssq2 = sums2 + 64;                                // 64
  float* msq = (float*)(ws + 22744576);                    // 40 f32 (= sums1+640, zeroed)
  unsigned* flags = (unsigned*)(ws + 22744736);            // 4 u32 (= sums1+680, zeroed)
  unsigned short* lufeatH = (unsigned short*)(ws + 25165824);  // 16384x1024 bf16 (32 MB)

  float* lscores = (float*)d_out;
  float* uscores = lscores + 8192;
  float* mbank = uscores + 8192;

  // prep: Weff(256) first, beff(1), W3T(320), W4T(64), statz+flags(1), hcvt(1024)
  prep_all<<<1666, 256, 0, stream>>>(lufeat, lufeatH, W1, W2, b1, b2, W3, W4,
                                     WeffT, beff, W3T, W4T, sums1);
  // main GEMM: pure-DMA bf16 A+B
  gemm1_dma<<<512, 256, 0, stream>>>(lufeatH, WeffT, beff, Hraw, uf);
  // fused back-half, flag-chained phases
  back_all<<<1824, 256, 0, stream>>>(
      llabel, Hraw, mbank0, start0, mbank, msq, lscores, uf,
      W3T, b3, ybuf, sums1, ssq1, g1, be1,
      W4T, b4, y2, sums2, ssq2, g2, be2,
      W5, b5, uscores, flags);
}

// Round 10
// 235.876 us; speedup vs baseline: 1.7486x; 1.7486x over previous
//
#include <hip/hip_runtime.h>
#include <hip/hip_bf16.h>
#include <stdint.h>

typedef __attribute__((ext_vector_type(4))) float f32x4;
typedef __attribute__((ext_vector_type(8))) short s16x8;
typedef __attribute__((ext_vector_type(4))) unsigned short u16x4;
typedef __attribute__((ext_vector_type(4))) int i32x4;

#define B2T 16384
#define BH 8192
#define DIN 1024
#define DD1 512
#define DIMS 256
#define NC 40
#define CAPS 2048

__device__ __forceinline__ unsigned short f2b(float f) {
  unsigned int u = __builtin_bit_cast(unsigned int, f);
  u += 0x7FFFu + ((u >> 16) & 1u);
  return (unsigned short)(u >> 16);
}

__device__ __forceinline__ float b2f(unsigned short u) {
  return __builtin_bit_cast(float, ((unsigned int)u) << 16);
}

// async global->LDS DMA, 16B per lane; LDS dst is wave-uniform base + lane*16
__device__ __forceinline__ void gload16(const void* g, void* l) {
  __builtin_amdgcn_global_load_lds(
      (const __attribute__((address_space(1))) void*)g,
      (__attribute__((address_space(3))) void*)l, 16, 0, 0);
}

// ---------------- prep_all: fused Weff tiles / beff / W3T / W4T / stat-zero -----------------
__global__ __launch_bounds__(256) void prep_all(const float* __restrict__ W1,
                                                const float* __restrict__ W2,
                                                const float* __restrict__ b1,
                                                const float* __restrict__ b2,
                                                const float* __restrict__ W3,
                                                const float* __restrict__ W4,
                                                unsigned short* __restrict__ WeffT,
                                                float* __restrict__ beff,
                                                unsigned short* __restrict__ W3T,
                                                unsigned short* __restrict__ W4T,
                                                float* __restrict__ statz) {
  __shared__ float W1s[32][36];
  __shared__ float W2sT[32][36];
  int b = blockIdx.x, t = threadIdx.x;
  if (b < 256) {
    int k0 = (b & 31) * 32, n0 = (b >> 5) * 32;
    int nn = t & 31, kq = t >> 5;  // kq in 0..7
    f32x4 acc = (f32x4){0.f, 0.f, 0.f, 0.f};
    for (int j0 = 0; j0 < DD1; j0 += 32) {
#pragma unroll
      for (int i = 0; i < 4; ++i) {
        int idx = t + 256 * i;
        int kk = idx >> 5, jj = idx & 31;
        W1s[kk][jj] = W1[(size_t)(k0 + kk) * DD1 + j0 + jj];
        W2sT[jj][kk] = W2[(size_t)(j0 + kk) * DIMS + n0 + jj];
      }
      __syncthreads();
#pragma unroll
      for (int jj4 = 0; jj4 < 8; ++jj4) {
        f32x4 w2 = *(const f32x4*)&W2sT[nn][jj4 * 4];
        f32x4 w1_0 = *(const f32x4*)&W1s[kq * 4 + 0][jj4 * 4];
        f32x4 w1_1 = *(const f32x4*)&W1s[kq * 4 + 1][jj4 * 4];
        f32x4 w1_2 = *(const f32x4*)&W1s[kq * 4 + 2][jj4 * 4];
        f32x4 w1_3 = *(const f32x4*)&W1s[kq * 4 + 3][jj4 * 4];
        acc[0] += w1_0[0] * w2[0] + w1_0[1] * w2[1] + w1_0[2] * w2[2] + w1_0[3] * w2[3];
        acc[1] += w1_1[0] * w2[0] + w1_1[1] * w2[1] + w1_1[2] * w2[2] + w1_1[3] * w2[3];
        acc[2] += w1_2[0] * w2[0] + w1_2[1] * w2[1] + w1_2[2] * w2[2] + w1_2[3] * w2[3];
        acc[3] += w1_3[0] * w2[0] + w1_3[1] * w2[1] + w1_3[2] * w2[2] + w1_3[3] * w2[3];
      }
      __syncthreads();
    }
    u16x4 pk = {f2b(acc[0]), f2b(acc[1]), f2b(acc[2]), f2b(acc[3])};
    *(u16x4*)(WeffT + (size_t)(n0 + nn) * DIN + k0 + kq * 4) = pk;
  } else if (b == 256) {
    float a0 = 0.f, a1 = 0.f, a2 = 0.f, a3 = 0.f, a4 = 0.f, a5 = 0.f, a6 = 0.f, a7 = 0.f;
    for (int j = 0; j < DD1; j += 8) {
      a0 += b1[j + 0] * W2[(size_t)(j + 0) * DIMS + t];
      a1 += b1[j + 1] * W2[(size_t)(j + 1) * DIMS + t];
      a2 += b1[j + 2] * W2[(size_t)(j + 2) * DIMS + t];
      a3 += b1[j + 3] * W2[(size_t)(j + 3) * DIMS + t];
      a4 += b1[j + 4] * W2[(size_t)(j + 4) * DIMS + t];
      a5 += b1[j + 5] * W2[(size_t)(j + 5) * DIMS + t];
      a6 += b1[j + 6] * W2[(size_t)(j + 6) * DIMS + t];
      a7 += b1[j + 7] * W2[(size_t)(j + 7) * DIMS + t];
    }
    beff[t] = b2[t] + (((a0 + a1) + (a2 + a3)) + ((a4 + a5) + (a6 + a7)));
  } else if (b < 577) {
    int idx = (b - 257) * 256 + t;
    int n = idx / 320, k = idx - n * 320;
    float v = (k < 296) ? W3[(size_t)k * 256 + n] : 0.0f;
    W3T[(size_t)n * 320 + k] = f2b(v);
  } else if (b < 641) {
    int idx = (b - 577) * 256 + t;
    int n = idx >> 8, k = idx & 255;
    W4T[(size_t)n * 256 + k] = f2b(W4[(size_t)k * 64 + n]);
  } else {
    for (int i = t; i < 640; i += 256) statz[i] = 0.0f;
  }
}

// ---------------- fused bf16 MFMA GEMM core, 1 counted-vmcnt barrier/K-step -----------------
// AMODE: 0=A fp32, 1=A bf16, 2=A fp32 + BN1 + ReLU (LDS table; K<=256)
// EPI:   1=rownorm; lower rows -> C f32, upper rows -> uf bf16 only
//        2/3=store+bnstat
// Counted barrier (T4): at each K-step barrier we drain only the B-DMAs (needed next step)
// and keep the A-prefetch (issued 2 steps ahead) in flight. Requires uniform A-issue
// (ACH>=TPB); else falls back to __syncthreads.
template <int AMODE, int NB, int MI, int CW, int EPI, int K, int TPB>
__global__ __launch_bounds__(TPB) void gemm_core(
    const void* __restrict__ Aptr, int lda, const unsigned short* __restrict__ BT,
    const float* __restrict__ bias, float* __restrict__ C, int ldc,
    float* __restrict__ sums, float* __restrict__ ssqs,
    const float* __restrict__ bnsum, const float* __restrict__ bnssq,
    const float* __restrict__ bng, const float* __restrict__ bnbe,
    unsigned short* __restrict__ uf) {
  constexpr int NW = TPB / 64;
  constexpr int RG = NW / CW;
  constexpr int AR = RG * MI * 16;        // rows per block
  constexpr int ACH = AR * 8;             // A 16B-units per k-step (8 elems each)
  constexpr int ABN = (ACH + TPB - 1) / TPB;
  constexpr int BBN = NB * 8 / TPB;       // B 16B-units per thread per k-step
  constexpr int BBUF = NB * 128;          // bytes per B k-step buffer
  constexpr int ALOADS = (AMODE == 1) ? ABN : 2 * ABN;  // per-thread A vmem ops per step
  constexpr bool UNIF = (ACH >= TPB);     // all threads issue A loads -> uniform vmcnt
  __shared__ __align__(16) short A_s[2][AR][72];
  __shared__ __align__(16) char B_s[2 * BBUF];
  __shared__ float rs[CW][AR];
  __shared__ float bsc_s[(AMODE == 2) ? 256 : 1];
  __shared__ float bsh_s[(AMODE == 2) ? 256 : 1];
  int t = threadIdx.x;
  int m0 = blockIdx.x * AR;
  int w = t >> 6, lane = t & 63, q = lane >> 4, ln = lane & 15;
  f32x4 acc[MI][4];
#pragma unroll
  for (int mi = 0; mi < MI; ++mi)
#pragma unroll
    for (int ni = 0; ni < 4; ++ni) acc[mi][ni] = (f32x4){0.f, 0.f, 0.f, 0.f};

  // two statically-named A register buffer sets (never runtime-indexed -> stay in VGPRs)
  f32x4 pa0[ABN][2], pa1[ABN][2];
  s16x8 pab0[ABN], pab1[ABN];

  auto issue = [&](int kbase, f32x4 (&paX)[ABN][2], s16x8 (&pabX)[ABN]) {
    if (ACH >= TPB || t < ACH) {
#pragma unroll
      for (int i = 0; i < ABN; ++i) {
        int ch = t + TPB * i, row = ch >> 3, kp = (ch & 7) * 8;
        if constexpr (AMODE == 1) {
          const unsigned short* A = (const unsigned short*)Aptr;
          pabX[i] = *(const s16x8*)(A + (size_t)(m0 + row) * lda + kbase + kp);
        } else {
          const float* A = (const float*)Aptr;
          const f32x4* src = (const f32x4*)(A + (size_t)(m0 + row) * lda + kbase + kp);
          paX[i][0] = src[0];
          paX[i][1] = src[1];
        }
      }
    }
  };

  // B: async DMA into linear LDS; source address pre-swizzled so that the
  // ds_read-side XOR (row&7)<<4 sees logical layout.
  auto gloadB = [&](int kbase, int bufi) {
#pragma unroll
    for (int i = 0; i < BBN; ++i) {
      int ch = t + TPB * i;
      int n = ch >> 3, j = ch & 7;
      int ksw = (j ^ (n & 7)) * 8;  // pre-swizzled k-offset (elements)
      gload16(BT + (size_t)n * K + kbase + ksw,
              B_s + bufi * BBUF + (w * 64 + TPB * i) * 16);
    }
  };

  auto stage = [&](int kk, int bufi, f32x4 (&paX)[ABN][2], s16x8 (&pabX)[ABN]) {
    if (ACH >= TPB || t < ACH) {
#pragma unroll
      for (int i = 0; i < ABN; ++i) {
        int ch = t + TPB * i, row = ch >> 3, kp = (ch & 7) * 8;
        if constexpr (AMODE == 1) {
          *(s16x8*)&A_s[bufi][row][kp] = pabX[i];
        } else {
          f32x4 v0 = paX[i][0], v1 = paX[i][1];
          if constexpr (AMODE == 2) {
            float vv[8] = {v0[0], v0[1], v0[2], v0[3], v1[0], v1[1], v1[2], v1[3]};
#pragma unroll
            for (int j = 0; j < 8; ++j) {
              int f = kk + kp + j;
              vv[j] = fmaxf(vv[j] * bsc_s[f] + bsh_s[f], 0.0f);
            }
            v0 = (f32x4){vv[0], vv[1], vv[2], vv[3]};
            v1 = (f32x4){vv[4], vv[5], vv[6], vv[7]};
          }
          s16x8 p;
          p[0] = (short)f2b(v0[0]); p[1] = (short)f2b(v0[1]);
          p[2] = (short)f2b(v0[2]); p[3] = (short)f2b(v0[3]);
          p[4] = (short)f2b(v1[0]); p[5] = (short)f2b(v1[1]);
          p[6] = (short)f2b(v1[2]); p[7] = (short)f2b(v1[3]);
          *(s16x8*)&A_s[bufi][row][kp] = p;
        }
      }
    }
  };

  auto compute = [&](int cur) {
#pragma unroll
    for (int k32 = 0; k32 < 64; k32 += 32) {
      s16x8 af[MI];
      int ab = (w / CW) * MI * 16;
#pragma unroll
      for (int mi = 0; mi < MI; ++mi)
        af[mi] = *(const s16x8*)&A_s[cur][ab + mi * 16 + ln][k32 + q * 8];
      int nb0 = (w % CW) * 64;
#pragma unroll
      for (int ni = 0; ni < 4; ++ni) {
        int brow = nb0 + ni * 16 + ln;
        int bb = (brow * 128 + (k32 + q * 8) * 2) ^ ((brow & 7) << 4);
        s16x8 bfr = *(const s16x8*)(B_s + cur * BBUF + bb);
#pragma unroll
        for (int mi = 0; mi < MI; ++mi)
          acc[mi][ni] = __builtin_amdgcn_mfma_f32_16x16x32_bf16(af[mi], bfr, acc[mi][ni], 0, 0, 0);
      }
    }
  };

  // K-step barrier: drain B (and ds_writes), keep the ALOADS newest (A prefetch) in flight.
  auto kbar = [&](bool keepA) {
    if constexpr (UNIF) {
      if (keepA)
        asm volatile("s_waitcnt vmcnt(%0) lgkmcnt(0)" ::"n"(ALOADS) : "memory");
      else
        asm volatile("s_waitcnt vmcnt(0) lgkmcnt(0)" ::: "memory");
      __builtin_amdgcn_s_barrier();
      __builtin_amdgcn_sched_barrier(0);
    } else {
      __syncthreads();
    }
  };

  if constexpr (AMODE == 2) {
    if (t < 256) {
      float mu = bnsum[t] * (1.0f / 8192.0f);
      float var = bnssq[t] * (1.0f / 8192.0f) - mu * mu;
      float sc = bng[t] * rsqrtf(var + 1e-5f);
      bsc_s[t] = sc;
      bsh_s[t] = bnbe[t] - mu * sc;
    }
    __syncthreads();
  }

  const int nst = K >> 6;
  issue(0, pa0, pab0);
  gloadB(0, 0);
  __builtin_amdgcn_sched_barrier(0);  // pin order: B(0) before A(1)
  if (nst > 1) issue(64, pa1, pab1);
  stage(0, 0, pa0, pab0);             // auto-waits A(0); B(0)+A(1) stay outstanding
  kbar(nst > 1);                      // drain B(0), keep A(1)

  for (int s = 0; s < nst; s += 2) {
    // even step: cur buf 0
    if (s + 1 < nst) gloadB((s + 1) << 6, 1);
    __builtin_amdgcn_sched_barrier(0);  // pin order: B(s+1) before A(s+2)
    if (s + 2 < nst) issue((s + 2) << 6, pa0, pab0);
    compute(0);
    if (s + 1 < nst) stage((s + 1) << 6, 1, pa1, pab1);  // auto-waits A(s+1)
    kbar(s + 2 < nst);                                   // drain B(s+1), keep A(s+2)
    if (s + 1 < nst) {
      // odd step: cur buf 1
      if (s + 2 < nst) gloadB((s + 2) << 6, 0);
      __builtin_amdgcn_sched_barrier(0);
      if (s + 3 < nst) issue((s + 3) << 6, pa1, pab1);
      compute(1);
      if (s + 2 < nst) stage((s + 2) << 6, 0, pa0, pab0);  // auto-waits A(s+2)
      kbar(s + 3 < nst);                                   // drain B(s+2), keep A(s+3)
    }
  }

  float v[MI][4][4];
#pragma unroll
  for (int mi = 0; mi < MI; ++mi)
#pragma unroll
    for (int ni = 0; ni < 4; ++ni) {
      float bv = bias[(w % CW) * 64 + ni * 16 + ln];
#pragma unroll
      for (int r = 0; r < 4; ++r) v[mi][ni][r] = acc[mi][ni][r] + bv;
    }

  if constexpr (EPI == 1) {
    float p[MI][4];
#pragma unroll
    for (int mi = 0; mi < MI; ++mi)
#pragma unroll
      for (int r = 0; r < 4; ++r) {
        float s = v[mi][0][r] * v[mi][0][r] + v[mi][1][r] * v[mi][1][r] +
                  v[mi][2][r] * v[mi][2][r] + v[mi][3][r] * v[mi][3][r];
        s += __shfl_xor(s, 1); s += __shfl_xor(s, 2);
        s += __shfl_xor(s, 4); s += __shfl_xor(s, 8);
        p[mi][r] = s;
      }
    if (ln == 0) {
#pragma unroll
      for (int mi = 0; mi < MI; ++mi)
#pragma unroll
        for (int r = 0; r < 4; ++r)
          rs[w % CW][(w / CW) * MI * 16 + mi * 16 + q * 4 + r] = p[mi][r];
    }
    __syncthreads();
    if (t < AR) {
      float s = rs[0][t];
#pragma unroll
      for (int i = 1; i < CW; ++i) s += rs[i][t];
      rs[0][t] = rsqrtf(s);
    }
    __syncthreads();
#pragma unroll
    for (int mi = 0; mi < MI; ++mi)
#pragma unroll
      for (int r = 0; r < 4; ++r) {
        int ribf = (w / CW) * MI * 16 + mi * 16 + q * 4 + r;
        float inv = rs[0][ribf];
        int grow = m0 + ribf;
#pragma unroll
        for (int ni = 0; ni < 4; ++ni) {
          int col = (w % CW) * 64 + ni * 16 + ln;
          float nv = v[mi][ni][r] * inv;
          if (grow < BH)
            C[(size_t)grow * ldc + col] = nv;            // lower half: f32 for bank+dist
          else
            uf[(size_t)(grow - BH) * 320 + col] = f2b(nv);  // upper half: bf16 only
        }
      }
  } else {
#pragma unroll
    for (int mi = 0; mi < MI; ++mi)
#pragma unroll
      for (int ni = 0; ni < 4; ++ni)
#pragma unroll
        for (int r = 0; r < 4; ++r) {
          int grow = m0 + (w / CW) * MI * 16 + mi * 16 + q * 4 + r;
          int col = (w % CW) * 64 + ni * 16 + ln;
          C[(size_t)grow * ldc + col] = v[mi][ni][r];
        }
    if constexpr (EPI == 2 || EPI == 3) {
#pragma unroll
      for (int ni = 0; ni < 4; ++ni) {
        float s = 0.f, s2 = 0.f;
#pragma unroll
        for (int mi = 0; mi < MI; ++mi)
#pragma unroll
          for (int r = 0; r < 4; ++r) {
            float x = v[mi][ni][r];
            s += x; s2 += x * x;
          }
        s += __shfl_xor(s, 16); s += __shfl_xor(s, 32);
        s2 += __shfl_xor(s2, 16); s2 += __shfl_xor(s2, 32);
        if (q == 0) {
          int col = (w % CW) * 64 + ni * 16 + ln;
          atomicAdd(&sums[col], s);
          atomicAdd(&ssqs[col], s2);
        }
      }
    }
  }
}

// ---------------- memory-bank EMA scan, closed form (single kernel, 40 blocks) --------------
__global__ __launch_bounds__(256) void bank_kernel(const int* __restrict__ llabel,
                                                   const float* __restrict__ Hn,
                                                   const float* __restrict__ mbank0,
                                                   const float* __restrict__ start0,
                                                   float* __restrict__ mbank_out,
                                                   float* __restrict__ msq) {
  __shared__ i32x4 lab4[BH / 4];  // 32 KB
  __shared__ int idx_s[CAPS];     // 8 KB
  __shared__ int wcnt[4];
  __shared__ float red[4];
  int t = threadIdx.x, c = blockIdx.x;
  int w = t >> 6, lane = t & 63;

  for (int i = t; i < BH / 4; i += 256) lab4[i] = ((const i32x4*)llabel)[i];
  __syncthreads();
  const int* lab_s = (const int*)lab4;

  int base0 = w * (BH / 4);
  int cnt = 0;
  for (int b = 0; b < BH / 4; b += 64)
    cnt += (int)__popcll(__ballot(lab_s[base0 + b + lane] == c));
  if (lane == 0) wcnt[w] = cnt;
  __syncthreads();
  int off = 0;
#pragma unroll
  for (int i = 0; i < 4; ++i)
    if (i < w) off += wcnt[i];
  int Ktot = wcnt[0] + wcnt[1] + wcnt[2] + wcnt[3];

  int running = off;
  for (int b = 0; b < BH / 4; b += 64) {
    bool hit = lab_s[base0 + b + lane] == c;
    unsigned long long mk = __ballot(hit);
    if (hit) {
      int pos = running + (int)__popcll(mk & ((1ull << lane) - 1ull));
      if (pos < CAPS) idx_s[pos] = base0 + b + lane;
    }
    running += (int)__popcll(mk);
  }
  __syncthreads();
  int K = Ktot < CAPS ? Ktot : CAPS;

  const float l09 = -0.15200309344504997f;  // log2(0.9)
  bool fresh = (start0[c] == 0.0f);
  float out;
  if (K == 0) {
    out = mbank0[(size_t)c * DIMS + t];
  } else {
    float a0 = 0.f, a1 = 0.f, a2 = 0.f, a3 = 0.f, a4 = 0.f, a5 = 0.f, a6 = 0.f, a7 = 0.f;
    float w0fold = fresh ? exp2f((float)K * l09) : 0.f;
    int m = 0;
    for (; m + 8 <= K; m += 8) {
      float e = (float)(K - 1 - m);
      float wa = 0.1f * exp2f(e * l09) + (m == 0 ? w0fold : 0.f);
      a0 += wa * Hn[(size_t)idx_s[m + 0] * DIMS + t];
      a1 += 0.1f * exp2f((e - 1.f) * l09) * Hn[(size_t)idx_s[m + 1] * DIMS + t];
      a2 += 0.1f * exp2f((e - 2.f) * l09) * Hn[(size_t)idx_s[m + 2] * DIMS + t];
      a3 += 0.1f * exp2f((e - 3.f) * l09) * Hn[(size_t)idx_s[m + 3] * DIMS + t];
      a4 += 0.1f * exp2f((e - 4.f) * l09) * Hn[(size_t)idx_s[m + 4] * DIMS + t];
      a5 += 0.1f * exp2f((e - 5.f) * l09) * Hn[(size_t)idx_s[m + 5] * DIMS + t];
      a6 += 0.1f * exp2f((e - 6.f) * l09) * Hn[(size_t)idx_s[m + 6] * DIMS + t];
      a7 += 0.1f * exp2f((e - 7.f) * l09) * Hn[(size_t)idx_s[m + 7] * DIMS + t];
    }
    for (; m < K; ++m) {
      float wa = 0.1f * exp2f((float)(K - 1 - m) * l09) + (m == 0 ? w0fold : 0.f);
      a0 += wa * Hn[(size_t)idx_s[m] * DIMS + t];
    }
    float acc = ((a0 + a1) + (a2 + a3)) + ((a4 + a5) + (a6 + a7));
    float base_v = fresh ? 0.f : exp2f((float)K * l09) * mbank0[(size_t)c * DIMS + t];
    out = acc + base_v;
  }
  mbank_out[(size_t)c * DIMS + t] = out;
  float vv = out * out;
#pragma unroll
  for (int o = 32; o; o >>= 1) vv += __shfl_xor(vv, o);
  if ((t & 63) == 0) red[t >> 6] = vv;
  __syncthreads();
  if (t == 0) msq[c] = (red[0] + red[1]) + (red[2] + red[3]);
}

// ---------------- distances: 32 rows/block, 256 threads -------------------------------------
// lower row-blocks read Hn (f32); upper row-blocks read uf (bf16) -- upper Hraw never written
__global__ __launch_bounds__(256) void dist_kernel(const float* __restrict__ Hn,
                                                   const float* __restrict__ mbank,
                                                   const float* __restrict__ msq,
                                                   float* __restrict__ lscores,
                                                   unsigned short* __restrict__ uf) {
  __shared__ float Ms[NC][260];
  __shared__ float Hs[32][260];
  __shared__ float msq_s[NC];
  int t = threadIdx.x;
  int r0 = blockIdx.x * 32;
  for (int e = t; e < NC * 64; e += 256) {
    int i = e >> 6, d0 = (e & 63) * 4;
    *(f32x4*)&Ms[i][d0] = *(const f32x4*)(mbank + (size_t)i * DIMS + d0);
  }
  if (r0 < BH) {
    for (int e = t; e < 32 * 64; e += 256) {
      int i = e >> 6, d0 = (e & 63) * 4;
      *(f32x4*)&Hs[i][d0] = *(const f32x4*)(Hn + (size_t)(r0 + i) * DIMS + d0);
    }
  } else {
    for (int e = t; e < 32 * 32; e += 256) {
      int i = e >> 5, d0 = (e & 31) * 8;
      s16x8 vb = *(const s16x8*)(uf + (size_t)(r0 - BH + i) * 320 + d0);
#pragma unroll
      for (int j = 0; j < 8; ++j) Hs[i][d0 + j] = b2f((unsigned short)vb[j]);
    }
  }
  if (t < NC) msq_s[t] = msq[t];
  __syncthreads();
  int r = t >> 3, c0 = (t & 7) * 5;
  float g0 = 0, g1 = 0, g2 = 0, g3 = 0, g4 = 0;
  for (int d = 0; d < DIMS; d += 4) {
    f32x4 f = *(const f32x4*)&Hs[r][d];
    f32x4 m0v = *(const f32x4*)&Ms[c0 + 0][d];
    f32x4 m1v = *(const f32x4*)&Ms[c0 + 1][d];
    f32x4 m2v = *(const f32x4*)&Ms[c0 + 2][d];
    f32x4 m3v = *(const f32x4*)&Ms[c0 + 3][d];
    f32x4 m4v = *(const f32x4*)&Ms[c0 + 4][d];
    g0 += f[0] * m0v[0] + f[1] * m0v[1] + f[2] * m0v[2] + f[3] * m0v[3];
    g1 += f[0] * m1v[0] + f[1] * m1v[1] + f[2] * m1v[2] + f[3] * m1v[3];
    g2 += f[0] * m2v[0] + f[1] * m2v[1] + f[2] * m2v[2] + f[3] * m2v[3];
    g3 += f[0] * m3v[0] + f[1] * m3v[1] + f[2] * m3v[2] + f[3] * m3v[3];
    g4 += f[0] * m4v[0] + f[1] * m4v[1] + f[2] * m4v[2] + f[3] * m4v[3];
  }
  int row = r0 + r;
  float d2[5];
  d2[0] = 1.0f + msq_s[c0 + 0] - 2.0f * g0;
  d2[1] = 1.0f + msq_s[c0 + 1] - 2.0f * g1;
  d2[2] = 1.0f + msq_s[c0 + 2] - 2.0f * g2;
  d2[3] = 1.0f + msq_s[c0 + 3] - 2.0f * g3;
  d2[4] = 1.0f + msq_s[c0 + 4] - 2.0f * g4;
  if (row < BH) {
    float mn = fminf(fminf(fminf(d2[0], d2[1]), fminf(d2[2], d2[3])), d2[4]);
    mn = fminf(mn, __shfl_xor(mn, 1, 8));
    mn = fminf(mn, __shfl_xor(mn, 2, 8));
    mn = fminf(mn, __shfl_xor(mn, 4, 8));
    if ((t & 7) == 0) lscores[row] = sqrtf(fmaxf(mn, 0.0f));
  } else {
    unsigned short* dst = uf + (size_t)(row - BH) * 320 + 256 + c0;
#pragma unroll
    for (int qq = 0; qq < 5; ++qq) dst[qq] = f2b(sqrtf(fmaxf(d2[qq], 0.0f)));
  }
}

// ---------------- final: uscores = relu(bn2(y2)) @ W5 + b5 ----------------------------------
__global__ __launch_bounds__(256) void uscore_bn(const float* __restrict__ y2,
                                                 const float* __restrict__ sums2,
                                                 const float* __restrict__ ssqs2,
                                                 const float* __restrict__ g2,
                                                 const float* __restrict__ be2,
                                                 const float* __restrict__ W5,
                                                 const float* __restrict__ b5,
                                                 float* __restrict__ out) {
  int t = threadIdx.x;
  int wv = t >> 6, lane = t & 63;
  int row = blockIdx.x * 4 + wv;
  float mu = sums2[lane] * (1.0f / 8192.0f);
  float var = ssqs2[lane] * (1.0f / 8192.0f) - mu * mu;
  float sc = g2[lane] * rsqrtf(var + 1e-5f);
  float sh = be2[lane] - mu * sc;
  float v = fmaxf(y2[(size_t)row * 64 + lane] * sc + sh, 0.0f) * W5[lane];
#pragma unroll
  for (int o = 32; o; o >>= 1) v += __shfl_xor(v, o);
  if (lane == 0) out[row] = v + b5[0];
}

extern "C" void kernel_launch(void* const* d_in, const int* in_sizes, int n_in,
                              void* d_out, int out_size, void* d_ws, size_t ws_size,
                              hipStream_t stream) {
  const float* lufeat = (const float*)d_in[0];
  const int* llabel = (const int*)d_in[1];
  const float* W1 = (const float*)d_in[2];
  const float* b1 = (const float*)d_in[3];
  const float* W2 = (const float*)d_in[4];
  const float* b2 = (const float*)d_in[5];
  const float* W3 = (const float*)d_in[6];
  const float* b3 = (const float*)d_in[7];
  const float* W4 = (const float*)d_in[8];
  const float* b4 = (const float*)d_in[9];
  const float* W5 = (const float*)d_in[10];
  const float* b5 = (const float*)d_in[11];
  const float* g1 = (const float*)d_in[12];
  const float* be1 = (const float*)d_in[13];
  const float* g2 = (const float*)d_in[14];
  const float* be2 = (const float*)d_in[15];
  const float* mbank0 = (const float*)d_in[16];
  const float* start0 = (const float*)d_in[17];

  // workspace layout (lifetimes checked — no cross-lifetime aliasing):
  char* ws = (char*)d_ws;
  unsigned short* WeffT = (unsigned short*)(ws + 0);       // [0, 524288)
  float* Hraw = (float*)(ws + 524288);                     // lower 8192x256 f32 only
  float* ybuf = (float*)(ws + 524288);                     // lower half of Hraw (dead after dist)
  float* y2 = (float*)(ws + 8912896);                      // upper region (never written as Hraw)
  unsigned short* uf = (unsigned short*)(ws + 17301504);   // 8192x320 bf16
  unsigned short* W3T = (unsigned short*)(ws + 22544384);  // 256x320 bf16
  unsigned short* W4T = (unsigned short*)(ws + 22708224);  // 64x256 bf16
  float* beff = (float*)(ws + 22740992);                   // 256 f32
  float* sums1 = (float*)(ws + 22742016);                  // 256 (zeroed by prep_all)
  float* ssq1 = sums1 + 256;                               // 256
  float* sums2 = ssq1 + 256;                               // 64
  float* ssq2 = sums2 + 64;                                // 64
  float* msq = (float*)(ws + 22744576);                    // 40 f32

  float* lscores = (float*)d_out;
  float* uscores = lscores + 8192;
  float* mbank = uscores + 8192;

  prep_all<<<642, 256, 0, stream>>>(W1, W2, b1, b2, W3, W4, WeffT, beff, W3T, W4T, sums1);
  // main GEMM: 512 blocks x 256 threads, 32x256 tile, counted-vmcnt barrier/K-step
  gemm_core<0, 256, 2, 4, 1, 1024, 256><<<512, 256, 0, stream>>>(
      lufeat, 1024, WeffT, beff, Hraw, 256,
      nullptr, nullptr, nullptr, nullptr, nullptr, nullptr, uf);
  bank_kernel<<<NC, 256, 0, stream>>>(llabel, Hraw, mbank0, start0, mbank, msq);
  dist_kernel<<<512, 256, 0, stream>>>(Hraw, mbank, msq, lscores, uf);
  // uf @ W3 + b3 -> ybuf, fused bnstat1: 256 blocks x 512 threads (non-uniform A -> syncthreads)
  gemm_core<1, 256, 1, 4, 2, 320, 512><<<256, 512, 0, stream>>>(
      uf, 320, W3T, b3, ybuf, 256,
      sums1, ssq1, nullptr, nullptr, nullptr, nullptr, nullptr);
  // relu(bn1(ybuf)) @ W4 + b4 -> y2, BN1 fused in staging, fused bnstat2 (uniform -> counted)
  gemm_core<2, 64, 1, 1, 3, 256, 256><<<128, 256, 0, stream>>>(
      ybuf, 256, W4T, b4, y2, 64,
      sums2, ssq2, sums1, ssq1, g1, be1, nullptr);
  uscore_bn<<<2048, 256, 0, stream>>>(y2, sums2, ssq2, g2, be2, W5, b5, uscores);
}